// Round 7
// baseline (450.600 us; speedup 1.0000x reference)
//
#include <hip/hip_runtime.h>
#include <hip/hip_bf16.h>

typedef unsigned short u16;
typedef unsigned int u32;
typedef __attribute__((ext_vector_type(8))) short bf16x8;
typedef __attribute__((ext_vector_type(4))) float f32x4;

#define T_DIM 2048
#define B_DIM 32
#define H_DIM 512

__device__ inline unsigned pack2(float a, float b) {
  union { __hip_bfloat162 h2; unsigned u; } c;
  c.h2 = __float22bfloat162_rn(make_float2(a, b));
  return c.u;
}

// Precompute: r[b*512+h] = hidden[b]·W1[h] + b_attn[h]; u[h] = W3[h]·W_cov;
// W2bf = bf16(W2) in FRAGMENT-MAJOR layout (unchanged, harness-verified).
__global__ __launch_bounds__(256) void prep_kernel(
    const float* __restrict__ hidden, const float* __restrict__ W_attn,
    const float* __restrict__ b_attn, const float* __restrict__ W_cov,
    u16* __restrict__ W2bf, float* __restrict__ r, float* __restrict__ u)
{
  const int tid = blockIdx.x * 256 + threadIdx.x;  // 0..65535
  const int pair = tid >> 2;                       // b*512 + h
  const int kq = tid & 3;
  const int b = pair >> 9, h = pair & 511;

  {
    const float* hid = hidden + b * 512 + kq * 128;
    const float* w1 = W_attn + (size_t)h * 1536 + kq * 128;
    float acc = 0.f;
    #pragma unroll 8
    for (int k = 0; k < 128; k += 4) {
      float4 x = *(const float4*)(hid + k);
      float4 w = *(const float4*)(w1 + k);
      acc += x.x * w.x + x.y * w.y + x.z * w.z + x.w * w.w;
    }
    acc += __shfl_xor(acc, 1);
    acc += __shfl_xor(acc, 2);
    if (kq == 0) r[pair] = acc + b_attn[h];
  }

  {
    int j0 = tid * 4;
    int hh = j0 >> 9, kk = j0 & 511;
    float4 w = *(const float4*)(W_attn + (size_t)hh * 1536 + 512 + kk);
    uint2 p;
    p.x = pack2(w.x, w.y);
    p.y = pack2(w.z, w.w);
    int f = hh >> 4, c = hh & 15;
    int ks = kk >> 5, quad = (kk >> 3) & 3, e = kk & 7;   // e in {0,4}
    *(uint2*)(W2bf + (size_t)((f * 16 + ks) * 64 + quad * 16 + c) * 8 + e) = p;
  }

  if (tid < 2048) {
    int h3 = tid >> 2;
    const float* w3 = W_attn + (size_t)h3 * 1536 + 1024 + kq * 128;
    const float* wc = W_cov + kq * 128;
    float su = 0.f;
    #pragma unroll 8
    for (int k = 0; k < 128; k += 4) {
      float4 a = *(const float4*)(w3 + k);
      float4 c = *(const float4*)(wc + k);
      su += a.x * c.x + a.y * c.y + a.z * c.z + a.w * c.w;
    }
    su += __shfl_xor(su, 1);
    su += __shfl_xor(su, 2);
    if (kq == 0) u[h3] = su;
  }
}

// v7 (resubmit — r6 bench was an infra failure, no data): r5's verified
// producer/consumer structure with register pressure fixed so neither path
// spills (r5's 509MB FETCH / 129MB WRITE was scratch traffic: 84 allocated
// VGPRs vs ~110 needed):
//  - producers stage each tile in 2 batches of 8 float4 (peak 32 regs in
//    flight; 4 waves x 8 x 16B x 64 lanes = 32KB/CU in flight, >= BDP share)
//  - consumers drop the rv[] preload; epilogue reads r from L2 (r0-r3 path,
//    never visible in FETCH)
// Everything else identical to the r5 kernel that PASSED on hardware:
// 256 persistent blocks (1/CU, 128KB LDS ring of 4 x 32KB bf16 slots),
// 12 waves = 4 producers + 8 consumers, monotone fill/done flags (same-block
// waves -> co-resident by construction, G16-safe), consumer K-loop = verified
// r0 math with B 2-deep from L2-resident fragment-major W2bf.
__global__ __launch_bounds__(768, 3) void gemm_score(
    const float* __restrict__ enc, const u16* __restrict__ W2bf,
    const float* __restrict__ r, const float* __restrict__ u,
    const float* __restrict__ vv, const float* __restrict__ cov,
    float* __restrict__ part)
{
  const int blk = blockIdx.x;            // owns t = blk*8 .. blk*8+7
  const int tid = threadIdx.x;
  const int lane = tid & 63;
  const int w = tid >> 6;                // 0..11

  __shared__ u16 As[4][32 * 512];        // 128 KB ring: 4 slots x 32KB bf16
  __shared__ int fill[4];                // producer-wave completions per slot
  __shared__ int done[4];                // consumer-wave completions per slot

  if (tid < 4) { fill[tid] = 0; done[tid] = 0; }
  __syncthreads();                       // once, all 12 waves — flag init only

  volatile int* vfill = (volatile int*)fill;
  volatile int* vdone = (volatile int*)done;

  if (w >= 8) {
    // ---------------- producers: waves 8-11 ----------------
    const int pw = w - 8;                     // 0..3
    const int row = pw * 8 + (lane >> 3);     // 0..31
    const int g0 = lane & 7;                  // base 16B-granule
    #pragma unroll 1
    for (int tl = 0; tl < 8; ++tl) {
      const int s = tl & 3, n = tl >> 2;
      if (n >= 1) {                           // slot reuse: wait consumers done
        while (vdone[s] < 8 * n) __builtin_amdgcn_s_sleep(1);
      }
      const int t = blk * 8 + tl;
      const float* gb = enc + ((size_t)t * 32 + row) * 512;
      #pragma unroll 1
      for (int half = 0; half < 2; ++half) {  // 2 batches of 8 float4 = 32 regs peak
        float4 ba[4], bbf[4];
        #pragma unroll
        for (int p = 0; p < 4; ++p) {
          int G = g0 + 8 * (half * 4 + p);
          ba[p]  = *(const float4*)(gb + G * 8);
          bbf[p] = *(const float4*)(gb + G * 8 + 4);
        }
        #pragma unroll
        for (int p = 0; p < 4; ++p) {
          int G = g0 + 8 * (half * 4 + p);
          uint4 pk;
          pk.x = pack2(ba[p].x,  ba[p].y);
          pk.y = pack2(ba[p].z,  ba[p].w);
          pk.z = pack2(bbf[p].x, bbf[p].y);
          pk.w = pack2(bbf[p].z, bbf[p].w);
          *(uint4*)&As[s][row * 512 + (G ^ (row & 7)) * 8] = pk;  // verified swizzle
        }
      }
      __threadfence_block();                  // ds_writes visible before flag
      if (lane == 0) atomicAdd(&fill[s], 1);
    }
  } else {
    // ---------------- consumers: waves 0-7 (n-slab w*64) ----------------
    const int quad = lane >> 4, col = lane & 15;
    const u16* bbase = W2bf + (size_t)w * 32768 + lane * 8;

    float uj[4], vj[4];
    #pragma unroll
    for (int j = 0; j < 4; ++j) {
      int gh = w * 64 + j * 16 + col;
      uj[j] = u[gh];
      vj[j] = vv[gh];
    }

    #pragma unroll 1
    for (int tl = 0; tl < 8; ++tl) {
      const int s = tl & 3, n = tl >> 2;
      const int t = blk * 8 + tl;
      while (vfill[s] < 4 * (n + 1)) __builtin_amdgcn_s_sleep(1);
      __threadfence_block();                  // acquire: no LDS-read hoist

      // K-loop: bf16 A from LDS slot, B 2-deep from L2. Verified r0 math.
      bf16x8 bb[2][4];
      #pragma unroll
      for (int j = 0; j < 4; ++j) {
        bb[0][j] = *(const bf16x8*)(bbase + j * 8192);
        bb[1][j] = *(const bf16x8*)(bbase + j * 8192 + 512);
      }
      f32x4 acc[2][4] = {};
      const u16* as = As[s];
      #pragma unroll
      for (int ks = 0; ks < 16; ++ks) {
        #pragma unroll
        for (int i = 0; i < 2; ++i) {
          int row = i * 16 + col;
          bf16x8 af = *(const bf16x8*)&as[row * 512 + ((ks * 4 + quad) ^ (col & 7)) * 8];
          #pragma unroll
          for (int j = 0; j < 4; ++j)
            acc[i][j] = __builtin_amdgcn_mfma_f32_16x16x32_bf16(af, bb[ks & 1][j], acc[i][j], 0, 0, 0);
        }
        if (ks < 14) {
          #pragma unroll
          for (int j = 0; j < 4; ++j)
            bb[ks & 1][j] = *(const bf16x8*)(bbase + j * 8192 + (ks + 2) * 512);
        }
      }

      // Epilogue: e = relu(acc + r + cov*u); partial = e·v over this wave's 64 h
      #pragma unroll
      for (int i = 0; i < 2; ++i) {
        #pragma unroll
        for (int reg = 0; reg < 4; ++reg) {
          int bl = i * 16 + quad * 4 + reg;    // C/D layout: row = quad*4 + reg
          float cv = cov[bl * 2048 + t];
          float sacc = 0.f;
          #pragma unroll
          for (int j = 0; j < 4; ++j) {
            float rv = r[bl * 512 + w * 64 + j * 16 + col];
            float e = acc[i][j][reg] + rv + cv * uj[j];
            e = fmaxf(e, 0.f);
            sacc += e * vj[j];
          }
          sacc += __shfl_xor(sacc, 1);
          sacc += __shfl_xor(sacc, 2);
          sacc += __shfl_xor(sacc, 4);
          sacc += __shfl_xor(sacc, 8);
          if (col == 0) part[(size_t)(w * 32 + bl) * 2048 + t] = sacc;
        }
      }
      __threadfence_block();                  // slot reads complete before flag
      if (lane == 0) atomicAdd(&done[s], 1);
    }
  }
}

// Softmax over T per batch + coverage update. 32 blocks x 256 threads.
// part layout [p][b][t]: sum the 8 wave-partials (verified r0 path).
__global__ __launch_bounds__(256) void softmax_kernel(
    const float* __restrict__ part, const float* __restrict__ cov, float* __restrict__ out)
{
  const int b = blockIdx.x;
  const int tid = threadIdx.x;
  const int lane = tid & 63, wid = tid >> 6;
  __shared__ float red[4];
  float loc[8];
  float lmax = -3.4e38f;
  #pragma unroll
  for (int i = 0; i < 8; ++i) {
    int t = tid + i * 256;
    float s = 0.f;
    #pragma unroll
    for (int p = 0; p < 8; ++p) s += part[(size_t)(p * 32 + b) * 2048 + t];
    loc[i] = s;
    lmax = fmaxf(lmax, s);
  }
  #pragma unroll
  for (int o = 32; o; o >>= 1) lmax = fmaxf(lmax, __shfl_xor(lmax, o));
  if (lane == 0) red[wid] = lmax;
  __syncthreads();
  float bmax = fmaxf(fmaxf(red[0], red[1]), fmaxf(red[2], red[3]));
  __syncthreads();
  float lsum = 0.f;
  #pragma unroll
  for (int i = 0; i < 8; ++i) { loc[i] = __expf(loc[i] - bmax); lsum += loc[i]; }
  #pragma unroll
  for (int o = 32; o; o >>= 1) lsum += __shfl_xor(lsum, o);
  if (lane == 0) red[wid] = lsum;
  __syncthreads();
  float inv = 1.0f / (red[0] + red[1] + red[2] + red[3]);
  #pragma unroll
  for (int i = 0; i < 8; ++i) {
    int t = tid + i * 256;
    float a = loc[i] * inv;
    out[b * 2048 + t] = a;                               // attn_weights [B,1,T]
    out[65536 + b * 2048 + t] = cov[b * 2048 + t] + a;   // coverage_new [B,T]
  }
}

extern "C" void kernel_launch(void* const* d_in, const int* in_sizes, int n_in,
                              void* d_out, int out_size, void* d_ws, size_t ws_size,
                              hipStream_t stream) {
  const float* hidden = (const float*)d_in[0];   // [1,B,H]
  const float* enc    = (const float*)d_in[1];   // [T,B,H]
  const float* cov    = (const float*)d_in[2];   // [B,T]
  const float* W_attn = (const float*)d_in[3];   // [H,3H]
  const float* b_attn = (const float*)d_in[4];   // [H]
  const float* vv     = (const float*)d_in[5];   // [H]
  const float* W_cov  = (const float*)d_in[6];   // [H,1]
  float* out = (float*)d_out;

  u16* W2bf = (u16*)d_ws;                              // 512 KB (fragment-major)
  float* r  = (float*)((char*)d_ws + 512 * 1024);      // 64 KB
  float* u  = r + 32 * 512;                            // 2 KB
  float* part = u + 512;                               // 8 * 65536 * 4 = 2 MB

  hipLaunchKernelGGL(prep_kernel, dim3(256), dim3(256), 0, stream,
                     hidden, W_attn, b_attn, W_cov, W2bf, r, u);
  hipLaunchKernelGGL(gemm_score, dim3(256), dim3(768), 0, stream,
                     enc, W2bf, r, u, vv, cov, part);
  hipLaunchKernelGGL(softmax_kernel, dim3(32), dim3(256), 0, stream,
                     part, cov, out);
}

// Round 8
// 256.102 us; speedup vs baseline: 1.7595x; 1.7595x over previous
//
#include <hip/hip_runtime.h>
#include <hip/hip_bf16.h>

typedef unsigned short u16;
typedef unsigned int u32;
typedef __attribute__((ext_vector_type(8))) short bf16x8;
typedef __attribute__((ext_vector_type(4))) float f32x4;

#define T_DIM 2048
#define B_DIM 32
#define H_DIM 512

__device__ inline unsigned pack2(float a, float b) {
  union { __hip_bfloat162 h2; unsigned u; } c;
  c.h2 = __float22bfloat162_rn(make_float2(a, b));
  return c.u;
}

// Precompute: r[b*512+h] = hidden[b]·W1[h] + b_attn[h]; u[h] = W3[h]·W_cov;
// W2bf = bf16(W2) in FRAGMENT-MAJOR layout (verified every round).
// v8: 8-way K-split per dot (was 4-way) -> 131072 threads, 2 waves/SIMD
// device-wide, half the per-thread serial chain: attacks prep's
// latency-bound 1-wave/SIMD regime.
__global__ __launch_bounds__(256) void prep_kernel(
    const float* __restrict__ hidden, const float* __restrict__ W_attn,
    const float* __restrict__ b_attn, const float* __restrict__ W_cov,
    u16* __restrict__ W2bf, float* __restrict__ r, float* __restrict__ u)
{
  const int tid = blockIdx.x * 256 + threadIdx.x;  // 0..131071
  const int pair = tid >> 3;                       // b*512 + h
  const int kq = tid & 7;
  const int b = pair >> 9, h = pair & 511;

  {
    const float* hid = hidden + b * 512 + kq * 64;
    const float* w1 = W_attn + (size_t)h * 1536 + kq * 64;
    float acc = 0.f;
    #pragma unroll 16
    for (int k = 0; k < 64; k += 4) {
      float4 x = *(const float4*)(hid + k);
      float4 w = *(const float4*)(w1 + k);
      acc += x.x * w.x + x.y * w.y + x.z * w.z + x.w * w.w;
    }
    acc += __shfl_xor(acc, 1);
    acc += __shfl_xor(acc, 2);
    acc += __shfl_xor(acc, 4);
    if (kq == 0) r[pair] = acc + b_attn[h];
  }

  if (tid < 65536) {                               // W2 repack (verified addressing)
    int j0 = tid * 4;
    int hh = j0 >> 9, kk = j0 & 511;
    float4 w = *(const float4*)(W_attn + (size_t)hh * 1536 + 512 + kk);
    uint2 p;
    p.x = pack2(w.x, w.y);
    p.y = pack2(w.z, w.w);
    int f = hh >> 4, c = hh & 15;
    int ks = kk >> 5, quad = (kk >> 3) & 3, e = kk & 7;   // e in {0,4}
    *(uint2*)(W2bf + (size_t)((f * 16 + ks) * 64 + quad * 16 + c) * 8 + e) = p;
  }

  if (tid < 4096) {                                // u[h] = W3[h]·W_cov, 8-way split
    int h3 = tid >> 3;
    const float* w3 = W_attn + (size_t)h3 * 1536 + 1024 + kq * 64;
    const float* wc = W_cov + kq * 64;
    float su = 0.f;
    #pragma unroll 16
    for (int k = 0; k < 64; k += 4) {
      float4 a = *(const float4*)(w3 + k);
      float4 c = *(const float4*)(wc + k);
      su += a.x * c.x + a.y * c.y + a.z * c.z + a.w * c.w;
    }
    su += __shfl_xor(su, 1);
    su += __shfl_xor(su, 2);
    su += __shfl_xor(su, 4);
    if (kq == 0) u[h3] = su;
  }
}

// v8 gemm = round-0 structure RESTORED exactly (best measured: 88us, clean
// traffic: 72MB FETCH) + the r2/r3-verified in-block final-score epilogue
// (WRITE 10MB -> 0.3MB, softmax single coalesced read). One block (512 thr,
// 8 waves) per 64-row m-tile. Staging: bulk-issue 16 float4 A-loads into
// registers, cvt -> bf16 LDS (XOR-swizzled), one barrier. K-loop barrier-free:
// each wave owns a 64-wide n-slab; B frags are coalesced 1KB loads from
// fragment-major W2bf (L2-resident), register double-buffered.
__global__ __launch_bounds__(512, 4) void gemm_score(
    const float* __restrict__ enc, const u16* __restrict__ W2bf,
    const float* __restrict__ r, const float* __restrict__ u,
    const float* __restrict__ vv, const float* __restrict__ cov,
    float* __restrict__ part)
{
  const int m0 = blockIdx.x * 64;
  const int tid = threadIdx.x;
  const int lane = tid & 63;
  const int w = tid >> 6;             // wave id 0..7 -> n-slab [w*64, w*64+64)
  const int quad = lane >> 4, col = lane & 15;

  __shared__ u16 As[64 * 512];        // 64 KB, [row][k] with 16B-group XOR swizzle

  // ---- Phase 1a: bulk-issue 16 float4 loads (wave w covers rows it*8+w) ----
  float4 buf[16];
  {
    const float* gbase = enc + (size_t)m0 * 512 + lane * 8;
    #pragma unroll
    for (int it = 0; it < 8; ++it) {
      const float* ga = gbase + (size_t)(it * 8 + w) * 512;
      buf[it * 2]     = *(const float4*)ga;
      buf[it * 2 + 1] = *(const float4*)(ga + 4);
    }
  }
  // ---- Phase 1b: convert + swizzled LDS write (one ds_write_b128 per it) ----
  #pragma unroll
  for (int it = 0; it < 8; ++it) {
    int row = it * 8 + w;
    uint4 p;
    p.x = pack2(buf[it * 2].x,     buf[it * 2].y);
    p.y = pack2(buf[it * 2].z,     buf[it * 2].w);
    p.z = pack2(buf[it * 2 + 1].x, buf[it * 2 + 1].y);
    p.w = pack2(buf[it * 2 + 1].z, buf[it * 2 + 1].w);
    *(uint4*)&As[row * 512 + (lane ^ (row & 7)) * 8] = p;
  }
  __syncthreads();

  // ---- Phase 2: K-loop, no barriers. B frags: coalesced 1KB loads, dbuf. ----
  f32x4 acc[4][4] = {};
  const u16* bbase = W2bf + (size_t)w * 32768 + lane * 8;  // chunk=512 u16

  bf16x8 bcur[4], bnxt[4];
  #pragma unroll
  for (int j = 0; j < 4; ++j)
    bcur[j] = *(const bf16x8*)(bbase + j * 8192);

  #pragma unroll
  for (int ks = 0; ks < 16; ++ks) {
    if (ks < 15) {
      #pragma unroll
      for (int j = 0; j < 4; ++j)
        bnxt[j] = *(const bf16x8*)(bbase + j * 8192 + (ks + 1) * 512);
    }
    #pragma unroll
    for (int i = 0; i < 4; ++i) {
      int row = i * 16 + col;
      bf16x8 af = *(const bf16x8*)&As[row * 512 + ((ks * 4 + quad) ^ (col & 7)) * 8];
      #pragma unroll
      for (int j = 0; j < 4; ++j)
        acc[i][j] = __builtin_amdgcn_mfma_f32_16x16x32_bf16(af, bcur[j], acc[i][j], 0, 0, 0);
    }
    #pragma unroll
    for (int j = 0; j < 4; ++j) bcur[j] = bnxt[j];
  }

  // ---- Epilogue: e = relu(acc + r[b,h] + cov[b,t]*u[h]); partial = e·v;
  //      then in-block reduce across 8 waves (As dead -> red overlay) so
  //      part holds FINAL score[b][t] (r2/r3-verified tail). ----
  float uj[4], vj[4];
  #pragma unroll
  for (int j = 0; j < 4; ++j) {
    int gh = w * 64 + j * 16 + col;
    uj[j] = u[gh];
    vj[j] = vv[gh];
  }

  __syncthreads();                 // all As reads done; safe to overlay red
  float* red = (float*)As;         // red[(isub*32 + b)*8 + w], 512 floats

  #pragma unroll
  for (int pr = 0; pr < 2; ++pr) {
    #pragma unroll
    for (int reg = 0; reg < 4; ++reg) {
      int b = pr * 16 + quad * 4 + reg;         // = m & 31 (m0 % 64 == 0)
      const float* rb = r + b * 512;
      float rbj[4];
      #pragma unroll
      for (int j = 0; j < 4; ++j) rbj[j] = rb[w * 64 + j * 16 + col];
      #pragma unroll
      for (int isub = 0; isub < 2; ++isub) {
        int i = pr + isub * 2;
        int t = (m0 >> 5) + isub;
        float cv = cov[b * 2048 + t];
        float s = 0.f;
        #pragma unroll
        for (int j = 0; j < 4; ++j) {
          float e = acc[i][j][reg] + rbj[j] + cv * uj[j];
          e = fmaxf(e, 0.f);
          s += e * vj[j];
        }
        s += __shfl_xor(s, 1);
        s += __shfl_xor(s, 2);
        s += __shfl_xor(s, 4);
        s += __shfl_xor(s, 8);
        if (col == 0) red[(isub * 32 + b) * 8 + w] = s;
      }
    }
  }
  __syncthreads();
  if (tid < 64) {
    int isub = tid >> 5, b = tid & 31;
    float s = 0.f;
    #pragma unroll
    for (int p = 0; p < 8; ++p) s += red[(isub * 32 + b) * 8 + p];
    part[(size_t)b * 2048 + (m0 >> 5) + isub] = s;   // final score[b][t]
  }
}

// Softmax over T per batch + coverage update. 32 blocks x 256 threads.
// part holds final scores [b][t] -> single coalesced read (verified r2/r3).
__global__ __launch_bounds__(256) void softmax_kernel(
    const float* __restrict__ part, const float* __restrict__ cov, float* __restrict__ out)
{
  const int b = blockIdx.x;
  const int tid = threadIdx.x;
  const int lane = tid & 63, wid = tid >> 6;
  __shared__ float red[4];
  float loc[8];
  float lmax = -3.4e38f;
  #pragma unroll
  for (int i = 0; i < 8; ++i) {
    int t = tid + i * 256;
    float s = part[(size_t)b * 2048 + t];
    loc[i] = s;
    lmax = fmaxf(lmax, s);
  }
  #pragma unroll
  for (int o = 32; o; o >>= 1) lmax = fmaxf(lmax, __shfl_xor(lmax, o));
  if (lane == 0) red[wid] = lmax;
  __syncthreads();
  float bmax = fmaxf(fmaxf(red[0], red[1]), fmaxf(red[2], red[3]));
  __syncthreads();
  float lsum = 0.f;
  #pragma unroll
  for (int i = 0; i < 8; ++i) { loc[i] = __expf(loc[i] - bmax); lsum += loc[i]; }
  #pragma unroll
  for (int o = 32; o; o >>= 1) lsum += __shfl_xor(lsum, o);
  if (lane == 0) red[wid] = lsum;
  __syncthreads();
  float inv = 1.0f / (red[0] + red[1] + red[2] + red[3]);
  #pragma unroll
  for (int i = 0; i < 8; ++i) {
    int t = tid + i * 256;
    float a = loc[i] * inv;
    out[b * 2048 + t] = a;                               // attn_weights [B,1,T]
    out[65536 + b * 2048 + t] = cov[b * 2048 + t] + a;   // coverage_new [B,T]
  }
}

extern "C" void kernel_launch(void* const* d_in, const int* in_sizes, int n_in,
                              void* d_out, int out_size, void* d_ws, size_t ws_size,
                              hipStream_t stream) {
  const float* hidden = (const float*)d_in[0];   // [1,B,H]
  const float* enc    = (const float*)d_in[1];   // [T,B,H]
  const float* cov    = (const float*)d_in[2];   // [B,T]
  const float* W_attn = (const float*)d_in[3];   // [H,3H]
  const float* b_attn = (const float*)d_in[4];   // [H]
  const float* vv     = (const float*)d_in[5];   // [H]
  const float* W_cov  = (const float*)d_in[6];   // [H,1]
  float* out = (float*)d_out;

  u16* W2bf = (u16*)d_ws;                              // 512 KB (fragment-major)
  float* r  = (float*)((char*)d_ws + 512 * 1024);      // 64 KB
  float* u  = r + 32 * 512;                            // 2 KB
  float* part = u + 512;                               // 32*2048*4 = 256 KB (final scores)

  hipLaunchKernelGGL(prep_kernel, dim3(512), dim3(256), 0, stream,
                     hidden, W_attn, b_attn, W_cov, W2bf, r, u);
  hipLaunchKernelGGL(gemm_score, dim3(1024), dim3(512), 0, stream,
                     enc, W2bf, r, u, vv, cov, part);
  hipLaunchKernelGGL(softmax_kernel, dim3(32), dim3(256), 0, stream,
                     part, cov, out);
}